// Round 1
// baseline (164.004 us; speedup 1.0000x reference)
//
#include <hip/hip_runtime.h>

// DyGFormer co-occurrence encoder — single fused kernel, ZERO workspace usage.
//
// Math: counts are per-batch histograms; the 2-layer MLP of a scalar count is a
// lookup table T'[c] = relu(c*W1+b1)@W2 + b2.
//   out_src[b,l,:] = T'[hist_src[sid]] + T'[hist_dst[sid]]   (sid==0 -> c=0)
//   out_dst[b,l,:] = T'[hist_src[did]] + T'[hist_dst[did]]
//
// Key bound: within one block, distinct count values looked up are <= 63
// (hist values of a 512-element list sum to 512 => <=31 distinct positive
// values per histogram; two histograms + zero => <=63). So a 64-slot
// compacted per-block LDS table always suffices — no global T, no second
// kernel, no d_ws traffic (avoids the 512 MiB ws re-poison fill seen in
// rocprof at ~86 us/iter).
//
// Memory floor: 128 MiB fp32 output write ≈ 21 us at 6.3 TB/s.

#define BB      256
#define LL      512
#define DD      128
#define NNODES  1024
#define SPLITS  4               // row-splits per batch -> 1024 blocks (4/CU)
#define ROWS_PER (LL / SPLITS)  // 128
#define CMAXP1  (LL + 1)        // counts in [0, 512]
#define TBL_SLOTS 64            // provably >= 1 + 2*31 distinct counts/block

typedef float f4x __attribute__((ext_vector_type(4)));  // native vec: NT-store OK

__global__ __launch_bounds__(256) void fused_encode_kernel(
    const int* __restrict__ src_ids, const int* __restrict__ dst_ids,
    const float* __restrict__ W1, const float* __restrict__ b1,
    const float* __restrict__ W2, const float* __restrict__ b2,
    float* __restrict__ out) {
  // LDS ~37 KB -> 4 blocks/CU (148 KB of 160 KB).
  // tbl (32 KB) aliases hist (8 KB): hist is dead before tbl is written.
  __shared__ __align__(16) float tbl[TBL_SLOTS * DD];  // 32768 B
  __shared__ int slotOf[CMAXP1];                       // 2052 B: -1 / flag / slot
  __shared__ int cnt[4 * ROWS_PER];                    // 2048 B: raw count -> slot
  __shared__ int cOf[TBL_SLOTS];                       // slot -> count value
  __shared__ int ns;

  int* hist = (int*)tbl;  // [0..1023]=src hist, [1024..2047]=dst hist

  const int batch = blockIdx.x >> 2;            // blockIdx / SPLITS
  const int split = blockIdx.x & (SPLITS - 1);
  const int tid   = threadIdx.x;

  // P0: zero hist + slot map
#pragma unroll
  for (int i = tid; i < 2 * NNODES; i += 256) hist[i] = 0;
  for (int i = tid; i < CMAXP1; i += 256) slotOf[i] = -1;
  if (tid == 0) ns = 0;
  __syncthreads();

  // P1: per-batch histograms (LDS atomics)
  const int* sb = src_ids + batch * LL;
  const int* db = dst_ids + batch * LL;
#pragma unroll
  for (int i = tid; i < LL; i += 256) {
    atomicAdd(&hist[sb[i]], 1);
    atomicAdd(&hist[NNODES + db[i]], 1);
  }
  __syncthreads();

  // P2: 512 count lookups for this split's rows + presence flags
  const int r0 = split * ROWS_PER;
#pragma unroll
  for (int i = tid; i < 4 * ROWS_PER; i += 256) {
    const int r  = i & (ROWS_PER - 1);
    const int g  = i >> 7;  // 0: sid@src, 1: sid@dst, 2: did@src, 3: did@dst
    const int id = (g < 2 ? sb : db)[r0 + r];
    const int c  = id ? hist[(g & 1) * NNODES + id] : 0;
    cnt[i] = c;
    slotOf[c] = 1;  // benign write race (idempotent flag)
  }
  __syncthreads();

  // P3: compact distinct counts -> slots (<= 63 by the sum bound)
  for (int c = tid; c < CMAXP1; c += 256) {
    if (slotOf[c] >= 0) {
      const int s = atomicAdd(&ns, 1);
      slotOf[c] = s;
      cOf[s] = c;
    }
  }
  __syncthreads();

  // P4: remap raw counts to slots (in place; slotOf is final)
#pragma unroll
  for (int i = tid; i < 4 * ROWS_PER; i += 256) cnt[i] = slotOf[cnt[i]];

  // P5: build the needed table rows in LDS (overwrites dead hist region).
  // Same accumulation order / fma contraction as the old global build_table,
  // so output bits are unchanged. W1/b1 loads are block-uniform -> s_load.
  {
    const int nslots = ns;
    const int e = tid & (DD - 1);
    for (int s = tid >> 7; s < nslots; s += 2) {
      const float fc = (float)cOf[s];
      float acc = b2[e];
#pragma unroll 16
      for (int d = 0; d < DD; ++d)
        acc = fmaf(fmaxf(fmaf(fc, W1[d], b1[d]), 0.0f), W2[d * DD + e], acc);
      tbl[s * DD + e] = acc;
    }
  }
  __syncthreads();

  // P6: stream output. 128-float rows as 32 f4x; 8 rows in flight / 256 thr.
  const int lane = tid & 31;   // f4x index within the row
  const int rsub = tid >> 5;   // 0..7
  float* out_s = out + ((size_t)batch * LL + r0) * DD;
  float* out_d = out_s + (size_t)BB * LL * DD;  // dst_feat region
  const f4x* tb = (const f4x*)tbl;

#pragma unroll 4
  for (int rr = rsub; rr < ROWS_PER; rr += 8) {
    const f4x a = tb[cnt[rr] * (DD / 4) + lane];
    const f4x b = tb[cnt[ROWS_PER + rr] * (DD / 4) + lane];
    const f4x c = tb[cnt[2 * ROWS_PER + rr] * (DD / 4) + lane];
    const f4x d = tb[cnt[3 * ROWS_PER + rr] * (DD / 4) + lane];
    __builtin_nontemporal_store(a + b, ((f4x*)(out_s + (size_t)rr * DD)) + lane);
    __builtin_nontemporal_store(c + d, ((f4x*)(out_d + (size_t)rr * DD)) + lane);
  }
}

extern "C" void kernel_launch(void* const* d_in, const int* in_sizes, int n_in,
                              void* d_out, int out_size, void* d_ws, size_t ws_size,
                              hipStream_t stream) {
  const int*   src = (const int*)d_in[0];
  const int*   dst = (const int*)d_in[1];
  const float* W1  = (const float*)d_in[2];  // (1, D)
  const float* b1  = (const float*)d_in[3];  // (D,)
  const float* W2  = (const float*)d_in[4];  // (D, D) row-major
  const float* b2  = (const float*)d_in[5];  // (D,)
  // d_ws intentionally untouched: no workspace writes -> nothing to re-poison.
  fused_encode_kernel<<<BB * SPLITS, 256, 0, stream>>>(
      src, dst, W1, b1, W2, b2, (float*)d_out);
}

// Round 2
// 161.277 us; speedup vs baseline: 1.0169x; 1.0169x over previous
//
#include <hip/hip_runtime.h>

// DyGFormer co-occurrence encoder — single fused kernel, ZERO workspace usage.
//
// Math: counts are per-batch histograms; the 2-layer MLP of a scalar count is
// a lookup table T'[c] = relu(c*W1+b1)@W2 + b2.
//   out_src[b,l,:] = T'[hist_src[sid]] + T'[hist_dst[sid]]   (sid==0 -> c=0)
//   out_dst[b,l,:] = T'[hist_src[did]] + T'[hist_dst[did]]
//
// Structure (v2): ONE 1024-thread block per batch (256 blocks = 1/CU).
//  - histogram + table build once per batch (v1 did it 4x per batch)
//  - packed hist: src count in low16, dst in high16 -> 4 KB
//  - direct-mapped LDS table by count value c<32 (presence = 32-bit mask);
//    counts >=32 (impossible for this data: Poisson(0.5) per bin, max ~7)
//    take a guaranteed per-row GEMV fallback with identical FMA order.
//  - LDS ~20.5 KB, preamble ~2-3 us, then pure NT-store stream at the
//    134 MB write floor (~21 us at 6.3 TB/s).
// The 512 MiB ws re-poison fill (~86 us) is unconditional harness overhead
// (confirmed round 1: present with zero ws usage) — not addressable here.

#define BB      256
#define LL      512
#define DD      128
#define NNODES  1024
#define TBL_C   32              // direct-mapped table covers counts 0..31

typedef float f4x __attribute__((ext_vector_type(4)));  // native vec: NT-store OK

// Full T'[c] row segment for one lane (4 elems), same FMA order as the fast
// path -> bitwise identical. Only reachable if some count >= 32.
__device__ __noinline__ f4x slow_row(int c, int lane,
                                     const float* __restrict__ W1,
                                     const float* __restrict__ b1,
                                     const float* __restrict__ W2,
                                     const float* __restrict__ b2) {
  const int e0 = lane * 4;
  f4x acc = { b2[e0], b2[e0 + 1], b2[e0 + 2], b2[e0 + 3] };
  for (int d = 0; d < DD; ++d) {
    const float h = fmaxf(fmaf((float)c, W1[d], b1[d]), 0.0f);
#pragma unroll
    for (int j = 0; j < 4; ++j) acc[j] = fmaf(h, W2[d * DD + e0 + j], acc[j]);
  }
  return acc;
}

__global__ __launch_bounds__(1024) void fused_encode_kernel(
    const int* __restrict__ src_ids, const int* __restrict__ dst_ids,
    const float* __restrict__ W1, const float* __restrict__ b1,
    const float* __restrict__ W2, const float* __restrict__ b2,
    float* __restrict__ out) {
  // LDS ~20.5 KB. hist (4 KB, packed) aliases tbl's first rows; hist is dead
  // before the table build overwrites it.
  __shared__ __align__(16) float tbl[TBL_C * DD];  // 16384 B
  __shared__ short cnt4[LL][4];                    //  4096 B
  __shared__ int bitc[TBL_C];                      //   128 B
  __shared__ int nb, mask;

  int* hist = (int*)tbl;  // [0..1023]: src count low16, dst count high16

  const int batch = blockIdx.x;
  const int tid   = threadIdx.x;

  // P0: zero hist (1024 threads cover exactly) + flags
  hist[tid] = 0;
  if (tid == 0) { nb = 0; mask = 0; }
  __syncthreads();

  // P1: packed per-batch histograms (LDS atomics, no carry: counts <= 512)
  const int* sb = src_ids + batch * LL;
  const int* db = dst_ids + batch * LL;
  if (tid < LL) atomicAdd(&hist[sb[tid]], 1);
  else          atomicAdd(&hist[db[tid - LL]], 0x10000);
  __syncthreads();

  // P2: 2048 count lookups + presence mask
#pragma unroll
  for (int i = tid; i < 4 * LL; i += 1024) {
    const int g  = i >> 9;        // 0: sid@src, 1: sid@dst, 2: did@src, 3: did@dst
    const int r  = i & (LL - 1);
    const int id = (g < 2 ? sb : db)[r];
    const int hv = id ? hist[id] : 0;
    const int c  = (g & 1) ? (hv >> 16) : (hv & 0xffff);
    cnt4[r][g] = (short)c;
    if (c < TBL_C) atomicOr(&mask, 1u << c);
  }
  __syncthreads();

  // P3: extract set bits (order irrelevant)
  if (tid < TBL_C && ((mask >> tid) & 1)) {
    const int p = atomicAdd(&nb, 1);
    bitc[p] = tid;
  }
  __syncthreads();

  // P4: build the present table rows (overwrites dead hist region).
  // Same accumulation order / fma contraction as before -> bits unchanged.
  {
    const int nrows = nb;
    const int e = tid & (DD - 1);
    for (int k = tid >> 7; k < nrows; k += 8) {
      const int   c  = bitc[k];
      const float fc = (float)c;
      float acc = b2[e];
#pragma unroll 16
      for (int d = 0; d < DD; ++d)
        acc = fmaf(fmaxf(fmaf(fc, W1[d], b1[d]), 0.0f), W2[d * DD + e], acc);
      tbl[c * DD + e] = acc;
    }
  }
  __syncthreads();

  // P5: stream output. 128-float rows as 32 f4x; 32 rows in flight / 1024 thr.
  const int lane = tid & 31;   // f4x index within the row
  const int rsub = tid >> 5;   // 0..31
  float* out_s = out + (size_t)batch * LL * DD;
  float* out_d = out_s + (size_t)BB * LL * DD;  // dst_feat region
  const f4x* tb = (const f4x*)tbl;

#pragma unroll 4
  for (int rr = rsub; rr < LL; rr += 32) {
    const int ca = cnt4[rr][0], cb = cnt4[rr][1];
    const int cc = cnt4[rr][2], cd = cnt4[rr][3];
    const f4x va = (ca < TBL_C) ? tb[ca * (DD / 4) + lane] : slow_row(ca, lane, W1, b1, W2, b2);
    const f4x vb = (cb < TBL_C) ? tb[cb * (DD / 4) + lane] : slow_row(cb, lane, W1, b1, W2, b2);
    const f4x vc = (cc < TBL_C) ? tb[cc * (DD / 4) + lane] : slow_row(cc, lane, W1, b1, W2, b2);
    const f4x vd = (cd < TBL_C) ? tb[cd * (DD / 4) + lane] : slow_row(cd, lane, W1, b1, W2, b2);
    __builtin_nontemporal_store(va + vb, ((f4x*)(out_s + (size_t)rr * DD)) + lane);
    __builtin_nontemporal_store(vc + vd, ((f4x*)(out_d + (size_t)rr * DD)) + lane);
  }
}

extern "C" void kernel_launch(void* const* d_in, const int* in_sizes, int n_in,
                              void* d_out, int out_size, void* d_ws, size_t ws_size,
                              hipStream_t stream) {
  const int*   src = (const int*)d_in[0];
  const int*   dst = (const int*)d_in[1];
  const float* W1  = (const float*)d_in[2];  // (1, D)
  const float* b1  = (const float*)d_in[3];  // (D,)
  const float* W2  = (const float*)d_in[4];  // (D, D) row-major
  const float* b2  = (const float*)d_in[5];  // (D,)
  // d_ws intentionally untouched.
  fused_encode_kernel<<<BB, 1024, 0, stream>>>(src, dst, W1, b1, W2, b2,
                                               (float*)d_out);
}